// Round 5
// baseline (882.530 us; speedup 1.0000x reference)
//
#include <hip/hip_runtime.h>

// MultiFeatureMOE: F=4, E=8, B=4096, D=512, H=1024, O=512.
// Round 12: K-extension. All prior structures ran K=512 per block (8-16 iters)
// and all landed ~500 TF (m102 short-K regime). This round lengthens the
// per-block K-loop with the verified 128x128/BK=32/3-slot counted-vmcnt ring:
//  - gemm1: block loops 4 experts, CONTINUOUS ring across expert boundaries
//    (64 iters); per-expert epilogue in a separate 4.3KB cb region using raw
//    asm ds ops + manual barriers (no compiler vmcnt(0) drain), overlapped
//    with next expert's in-flight stages. 53.5KB LDS -> 3 blocks/CU.
//  - gemm2: block sums 4 experts (true K-dim): K=4096 = 128 iters. Epilogue once.
//  - merged-f single dispatch for each GEMM (ws-guarded; per-f fallback).
//  - 64B-row LDS swizzle fixed by bank analysis: read chunk q^((lr>>1)&3),
//    store chunk (t&3)^((rr>>1)&3) -> conflict-free ds_read_b128.

#define F_ 4
#define E_ 8
#define B_ 4096
#define D_ 512
#define H_ 1024
#define O_ 512

typedef unsigned short ushort_t;
typedef __bf16 bf16x8 __attribute__((ext_vector_type(8)));
typedef float f32x4 __attribute__((ext_vector_type(4)));
typedef unsigned short ushort8_t __attribute__((ext_vector_type(8)));
typedef unsigned uint2_ __attribute__((ext_vector_type(2)));

__device__ inline ushort_t f2bf(float f) {
  union { float f; unsigned u; } v; v.f = f;
  unsigned r = v.u + 0x7FFFu + ((v.u >> 16) & 1u);  // RNE
  return (ushort_t)(r >> 16);
}
__device__ inline float bf2f(ushort_t u) {
  union { unsigned u; float f; } v; v.u = ((unsigned)u) << 16;
  return v.f;
}

__device__ inline void async16(const void* g, void* l) {
  __builtin_amdgcn_global_load_lds(
      (const __attribute__((address_space(1))) unsigned int*)g,
      (__attribute__((address_space(3))) unsigned int*)l, 16, 0, 0);
}

__device__ inline unsigned ldsOff(const void* p) {
  return (unsigned)(unsigned long long)(const __attribute__((address_space(3))) char*)p;
}
// raw LDS ops — invisible to SIInsertWaitcnts' LDS-DMA alias tracking
__device__ inline bf16x8 dsr128(unsigned byteOff) {
  bf16x8 r;
  asm volatile("ds_read_b128 %0, %1" : "=v"(r) : "v"(byteOff));
  return r;
}
__device__ inline void dsw64(unsigned byteOff, uint2_ v) {
  asm volatile("ds_write_b64 %0, %1" :: "v"(byteOff), "v"(v) : "memory");
}

#define LGKM0 asm volatile("s_waitcnt lgkmcnt(0)" ::: "memory")
#define VM8 asm volatile("s_waitcnt vmcnt(8)" ::: "memory")
#define VM4 asm volatile("s_waitcnt vmcnt(4)" ::: "memory")
#define VM0 asm volatile("s_waitcnt vmcnt(0)" ::: "memory")
#define VNONE ((void)0)
#define SCB __builtin_amdgcn_sched_barrier(0)
#define SBAR __builtin_amdgcn_s_barrier()
// epilogue barrier: lgkm drain + barrier, NO vmcnt touch (ring stays in flight)
#define EBAR { SCB; LGKM0; asm volatile("" ::: "memory"); SBAR; SCB; }

// ---------------- prep: gate softmax (fp32) + feature bf16 cast, fused ----------------
__global__ void prep_kernel(const float* __restrict__ features, const float* __restrict__ Wg,
                            const float* __restrict__ bg, float* __restrict__ g2,
                            ushort_t* __restrict__ featbf) {
  const int fb = blockIdx.x;
  const int f = fb >> 12, b = fb & (B_ - 1);
  const int lane = threadIdx.x;
  const float* feat = features + ((size_t)f * B_ + b) * D_;
  const float* wg = Wg + (size_t)f * D_ * E_;
  const int d0 = lane * 8;
  float ff[8];
  *(float4*)&ff[0] = *(const float4*)&feat[d0];
  *(float4*)&ff[4] = *(const float4*)&feat[d0 + 4];
  ushort8_t u;
#pragma unroll
  for (int k = 0; k < 8; ++k) u[k] = f2bf(ff[k]);
  *(ushort8_t*)&featbf[((size_t)f * B_ + b) * D_ + d0] = u;

  float acc[E_] = {0.f, 0.f, 0.f, 0.f, 0.f, 0.f, 0.f, 0.f};
#pragma unroll
  for (int k = 0; k < 8; ++k) {
    const float fv = ff[k];
    const float4 w0 = ((const float4*)(wg + (size_t)(d0 + k) * E_))[0];
    const float4 w1 = ((const float4*)(wg + (size_t)(d0 + k) * E_))[1];
    acc[0] += fv * w0.x; acc[1] += fv * w0.y; acc[2] += fv * w0.z; acc[3] += fv * w0.w;
    acc[4] += fv * w1.x; acc[5] += fv * w1.y; acc[6] += fv * w1.z; acc[7] += fv * w1.w;
  }
#pragma unroll
  for (int off = 32; off >= 1; off >>= 1)
#pragma unroll
    for (int e = 0; e < E_; ++e) acc[e] += __shfl_xor(acc[e], off, 64);
  float lg[E_], mx = -1e30f;
#pragma unroll
  for (int e = 0; e < E_; ++e) { lg[e] = acc[e] + bg[f * E_ + e]; mx = fmaxf(mx, lg[e]); }
  float s = 0.f;
#pragma unroll
  for (int e = 0; e < E_; ++e) { lg[e] = __expf(lg[e] - mx); s += lg[e]; }
  const float inv = 1.f / (s * (float)F_);
  if (lane < E_) g2[((size_t)f * B_ + b) * E_ + lane] = lg[lane] * inv;
}

// ------------- batched transpose+cast: [R][C] fp32 -> [C][R] bf16 -------------
__global__ void transpose_cast_kernel(const float* __restrict__ in, ushort_t* __restrict__ out,
                                      int R, int C) {
  __shared__ float tile[64][65];
  const size_t zoff = (size_t)blockIdx.z * R * C;
  in += zoff; out += zoff;
  const int tx = threadIdx.x & 63, ty = threadIdx.x >> 6;
  const int r0 = blockIdx.y * 64, c0 = blockIdx.x * 64;
#pragma unroll
  for (int i = 0; i < 16; ++i) {
    const int r = ty + i * 4;
    tile[r][tx] = in[(size_t)(r0 + r) * C + c0 + tx];
  }
  __syncthreads();
#pragma unroll
  for (int i = 0; i < 16; ++i) {
    const int c = ty + i * 4;
    out[(size_t)(c0 + c) * R + r0 + tx] = f2bf(tile[tx][c]);
  }
}

// ================= GEMM engines: 128x128 tile, BK=32, 3-slot ring + cb region =================
// LDS: 3 slots x 16KB (A[128][32] @0, B[128][32] @8192B per slot) + cb 16x136 ush @49152B.
// Total 53504 B -> 3 blocks/CU. Tile tt -> slot tt%3; iter tt: {8 asm ds_read_b128;
// lgkm0; 16 MFMA; barrier; stage tile tt+3 (same slot); vmcnt(8); barrier}.
// Swizzle: store phys chunk t&3 <- source chunk (t&3)^((rr>>1)&3); read chunk
// q^((lr>>1)&3) -> every consecutive-8-lane group covers 8 distinct 16B columns.
// acc[i][j]: m = wm*64+i*16+lr, n = wn*64+j*16+q*4+{0..3}.

#define KITER(STAGEEXPR, VMS) { \
    const unsigned sb = ldsB + soff; \
    bf16x8 af[4], bfr[4]; \
    _Pragma("unroll") for (int i_ = 0; i_ < 4; ++i_) af[i_] = dsr128(sb + aRd + i_ * 1024u); \
    _Pragma("unroll") for (int j_ = 0; j_ < 4; ++j_) bfr[j_] = dsr128(sb + bRd + j_ * 1024u); \
    LGKM0; SCB; \
    __builtin_amdgcn_s_setprio(1); \
    _Pragma("unroll") for (int i_ = 0; i_ < 4; ++i_) \
      _Pragma("unroll") for (int j_ = 0; j_ < 4; ++j_) \
        acc[i_][j_] = __builtin_amdgcn_mfma_f32_16x16x32_bf16(bfr[j_], af[i_], acc[i_][j_], 0, 0, 0); \
    __builtin_amdgcn_s_setprio(0); \
    SCB; asm volatile("" ::: "memory"); SBAR; SCB; \
    STAGEEXPR; \
    VMS; \
    asm volatile("" ::: "memory"); SBAR; SCB; \
    ++tt; soff = (soff >= 32768u) ? 0u : (soff + 16384u); }

// ---------------- GEMM1: Hf[fi][e][m][h] = bf16(g2 * relu(feat @ W1t + b1)) ----------------
// grid: id = [fi:2][eg:1][s:8]; block loops experts e0..e0+3 (64 K-iters continuous).

#define STAGE1T(T3, SOFF) { const int t3 = (T3); \
    const ushort_t* a_ = aG + (t3 & 15) * 32; \
    const ushort_t* b_ = bG + (size_t)(t3 >> 4) * ((size_t)H_ * D_) + (t3 & 15) * 32; \
    char* s_ = (char*)lds + (SOFF); \
    async16(a_,            s_ + t * 16); \
    async16(a_ + 64 * D_,  s_ + 4096 + t * 16); \
    async16(b_,            s_ + 8192 + t * 16); \
    async16(b_ + 64 * D_,  s_ + 12288 + t * 16); }
#define STAGE1 STAGE1T(tt + 3, soff)

__global__ __launch_bounds__(256, 3) void gemm1_kernel(
    const ushort_t* __restrict__ featbf, const ushort_t* __restrict__ w1t,
    const float* __restrict__ b1, const float* __restrict__ g2,
    ushort_t* __restrict__ Hf, int fBase, size_t hfStride) {
  __shared__ __align__(16) ushort_t lds[26752];  // 53504 B
  const int id = blockIdx.x;
  const int s = id & 255;
  const int e0 = ((id >> 8) & 1) * 4;
  const int fi = (id >> 9) & 3;
  const int f = fBase + fi;
  const int n0 = (s & 7) * 128;   // h
  const int m0 = (s >> 3) * 128;  // b
  const ushort_t* A  = featbf + (size_t)f * B_ * D_;
  const float* g2f = g2 + (size_t)f * B_ * E_;
  ushort_t* HfF = Hf + (size_t)fi * hfStride;

  const int t = threadIdx.x, lane = t & 63, w = t >> 6;
  const int wm = w & 1, wn = w >> 1;
  const int lr = lane & 15, q = lane >> 4;
  const unsigned ldsB = ldsOff(lds);
  const unsigned cRd = (unsigned)((q ^ ((lr >> 1) & 3)) << 4);
  const unsigned aRd = (unsigned)((wm * 64 + lr) * 64) + cRd;
  const unsigned bRd = 8192u + (unsigned)((wn * 64 + lr) * 64) + cRd;
  const unsigned cbB = 49152u;

  const int rr = t >> 2;                        // 0..63
  const int cc = (t & 3) ^ ((rr >> 1) & 3);     // staging source chunk
  const ushort_t* aG = A + (size_t)(m0 + rr) * D_ + cc * 8;
  const ushort_t* bG = w1t + ((size_t)f * E_ + e0) * ((size_t)H_ * D_) +
                       (size_t)(n0 + rr) * D_ + cc * 8;

  f32x4 acc[4][4];
#pragma unroll
  for (int i = 0; i < 4; ++i)
#pragma unroll
    for (int j = 0; j < 4; ++j) acc[i][j] = (f32x4){0.f, 0.f, 0.f, 0.f};

  // prologue: stage tiles 0,1,2 -> slots 0,1,2; tile0 ready at <=8 outstanding
  STAGE1T(0, 0u); STAGE1T(1, 16384u); STAGE1T(2, 32768u);
  VM8;
  asm volatile("" ::: "memory"); SBAR; SCB;

  int tt = 0; unsigned soff = 0;
  for (int eg = 0; eg < 4; ++eg) {
    if (eg < 3) {
      for (int kk = 0; kk < 16; ++kk) KITER(STAGE1, VM8);
    } else {
      for (int kk = 0; kk < 13; ++kk) KITER(STAGE1, VM8);   // tt 48..60 stage 51..63
      KITER(VNONE, VM4);   // tt 61
      KITER(VNONE, VM0);   // tt 62
      KITER(VNONE, VNONE); // tt 63
    }
    // ---- epilogue for expert e = e0+eg (cb region; ring DMA stays in flight) ----
    const int e = e0 + eg;
    const float* b1e = b1 + ((size_t)f * E_ + e) * H_;
    ushort_t* HfEe = HfF + (size_t)e * B_ * H_;
#pragma unroll
    for (int pr = 0; pr < 8; ++pr) {
      if (wm == (pr >> 2)) {
        const int I = pr & 3;
        const float gv = g2f[(size_t)(m0 + pr * 16 + lr) * E_ + e];
#pragma unroll
        for (int j = 0; j < 4; ++j) {
          const int nl = wn * 64 + j * 16 + q * 4;
          const float4 bb = *(const float4*)&b1e[n0 + nl];
          const unsigned p0 = (unsigned)f2bf(fmaxf(acc[I][j][0] + bb.x, 0.f) * gv) |
                              ((unsigned)f2bf(fmaxf(acc[I][j][1] + bb.y, 0.f) * gv) << 16);
          const unsigned p1 = (unsigned)f2bf(fmaxf(acc[I][j][2] + bb.z, 0.f) * gv) |
                              ((unsigned)f2bf(fmaxf(acc[I][j][3] + bb.w, 0.f) * gv) << 16);
          dsw64(cbB + (unsigned)(lr * 272 + nl * 2), (uint2_){p0, p1});
        }
      }
      EBAR;
      {
        const int row = t >> 4, seg = t & 15;
        const bf16x8 rv = dsr128(cbB + (unsigned)(row * 272 + seg * 16));
        LGKM0; SCB;
        *(ushort8_t*)(HfEe + (size_t)(m0 + pr * 16 + row) * H_ + n0 + seg * 8) =
            __builtin_bit_cast(ushort8_t, rv);
      }
      EBAR;
    }
#pragma unroll
    for (int i = 0; i < 4; ++i)
#pragma unroll
      for (int j = 0; j < 4; ++j) acc[i][j] = (f32x4){0.f, 0.f, 0.f, 0.f};
  }
}

// ------- GEMM2: part[f*2+grp] = sum_{e in e0..e0+3} Hf_e @ W2t_e + sum g_e*b2_e -------
// grid: id = [fi:2][grp:1][s:7]; K = 4 experts x 1024 = 4096 -> 128 iters.

#define STAGE2T(T3, SOFF) { const int t3 = (T3); \
    const ushort_t* a_ = HfFe + (size_t)(t3 >> 5) * ((size_t)B_ * H_) + aOff + (t3 & 31) * 32; \
    const ushort_t* b_ = w2Fe + (size_t)(t3 >> 5) * ((size_t)O_ * H_) + bOff + (t3 & 31) * 32; \
    char* s_ = (char*)lds + (SOFF); \
    async16(a_,            s_ + t * 16); \
    async16(a_ + 64 * H_,  s_ + 4096 + t * 16); \
    async16(b_,            s_ + 8192 + t * 16); \
    async16(b_ + 64 * H_,  s_ + 12288 + t * 16); }
#define STAGE2 STAGE2T(tt + 3, soff)

__global__ __launch_bounds__(256, 3) void gemm2_kernel(
    const ushort_t* __restrict__ Hf, const ushort_t* __restrict__ w2t,
    const float* __restrict__ b2, const float* __restrict__ g2,
    ushort_t* __restrict__ part, int fBase, size_t hfStride) {
  __shared__ __align__(16) ushort_t lds[26752];  // 53504 B
  const int id = blockIdx.x;
  const int s = id & 127;
  const int grp = (id >> 7) & 1;
  const int fi = (id >> 8) & 3;
  const int f = fBase + fi;
  const int n0 = (s & 3) * 128;   // o
  const int m0 = (s >> 2) * 128;  // b
  const int e0 = grp * 4;
  const float* g2f = g2 + (size_t)f * B_ * E_;
  const ushort_t* HfFe = Hf + (size_t)fi * hfStride + (size_t)e0 * B_ * H_;
  const ushort_t* w2Fe = w2t + ((size_t)f * E_ + e0) * ((size_t)O_ * H_);

  const int t = threadIdx.x, lane = t & 63, w = t >> 6;
  const int wm = w & 1, wn = w >> 1;
  const int lr = lane & 15, q = lane >> 4;
  const unsigned ldsB = ldsOff(lds);
  const unsigned cRd = (unsigned)((q ^ ((lr >> 1) & 3)) << 4);
  const unsigned aRd = (unsigned)((wm * 64 + lr) * 64) + cRd;
  const unsigned bRd = 8192u + (unsigned)((wn * 64 + lr) * 64) + cRd;
  const unsigned cbB = 49152u;

  const int rr = t >> 2;
  const int cc = (t & 3) ^ ((rr >> 1) & 3);
  const size_t aOff = (size_t)(m0 + rr) * H_ + cc * 8;
  const size_t bOff = (size_t)(n0 + rr) * H_ + cc * 8;

  f32x4 acc[4][4];
#pragma unroll
  for (int i = 0; i < 4; ++i)
#pragma unroll
    for (int j = 0; j < 4; ++j) acc[i][j] = (f32x4){0.f, 0.f, 0.f, 0.f};

  STAGE2T(0, 0u); STAGE2T(1, 16384u); STAGE2T(2, 32768u);
  VM8;
  asm volatile("" ::: "memory"); SBAR; SCB;

  int tt = 0; unsigned soff = 0;
  for (int kk = 0; kk < 125; ++kk) KITER(STAGE2, VM8);  // tt 0..124
  KITER(VNONE, VM4);    // tt 125
  KITER(VNONE, VM0);    // tt 126
  KITER(VNONE, VNONE);  // tt 127

  // ---- epilogue (once): acc + sum_k g_k*b2_k -> cb -> part slab ----
  const float* b2e0 = b2 + ((size_t)f * E_ + e0) * O_;
  ushort_t* dstP = part + (size_t)(f * 2 + grp) * ((size_t)B_ * O_);
#pragma unroll
  for (int pr = 0; pr < 8; ++pr) {
    if (wm == (pr >> 2)) {
      const int I = pr & 3;
      const size_t gr = (size_t)(m0 + pr * 16 + lr) * E_ + e0;
      const float g0 = g2f[gr], g1 = g2f[gr + 1], g2v = g2f[gr + 2], g3 = g2f[gr + 3];
#pragma unroll
      for (int j = 0; j < 4; ++j) {
        const int nl = wn * 64 + j * 16 + q * 4;
        const int n = n0 + nl;
        const float4 c0 = *(const float4*)&b2e0[n];
        const float4 c1 = *(const float4*)&b2e0[O_ + n];
        const float4 c2 = *(const float4*)&b2e0[2 * O_ + n];
        const float4 c3 = *(const float4*)&b2e0[3 * O_ + n];
        const float r0 = acc[I][j][0] + g0 * c0.x + g1 * c1.x + g2v * c2.x + g3 * c3.x;
        const float r1 = acc[I][j][1] + g0 * c0.y + g1 * c1.y + g2v * c2.y + g3 * c3.y;
        const float r2 = acc[I][j][2] + g0 * c0.z + g1 * c1.z + g2v * c2.z + g3 * c3.z;
        const float r3 = acc[I][j][3] + g0 * c0.w + g1 * c1.w + g2v * c2.w + g3 * c3.w;
        const unsigned p0 = (unsigned)f2bf(r0) | ((unsigned)f2bf(r1) << 16);
        const unsigned p1 = (unsigned)f2bf(r2) | ((unsigned)f2bf(r3) << 16);
        dsw64(cbB + (unsigned)(lr * 272 + nl * 2), (uint2_){p0, p1});
      }
    }
    EBAR;
    {
      const int row = t >> 4, seg = t & 15;
      const bf16x8 rv = dsr128(cbB + (unsigned)(row * 272 + seg * 16));
      LGKM0; SCB;
      *(ushort8_t*)(dstP + (size_t)(m0 + pr * 16 + row) * O_ + n0 + seg * 8) =
          __builtin_bit_cast(ushort8_t, rv);
    }
    EBAR;
  }
}

// ---------------- final reduce: out = sum over 8 bf16 slabs ----------------
__global__ void reduce_kernel(const ushort_t* __restrict__ part, float* __restrict__ out) {
  const size_t p = ((size_t)blockIdx.x * 256 + threadIdx.x) * 8;
  float s[8] = {0.f, 0.f, 0.f, 0.f, 0.f, 0.f, 0.f, 0.f};
#pragma unroll
  for (int k = 0; k < F_ * 2; ++k) {
    const ushort8_t u = *(const ushort8_t*)&part[(size_t)k * (B_ * O_) + p];
#pragma unroll
    for (int j = 0; j < 8; ++j) s[j] += bf2f(u[j]);
  }
  float4 o0 = {s[0], s[1], s[2], s[3]}, o1 = {s[4], s[5], s[6], s[7]};
  *(float4*)&out[p] = o0;
  *(float4*)&out[p + 4] = o1;
}

extern "C" void kernel_launch(void* const* d_in, const int* in_sizes, int n_in,
                              void* d_out, int out_size, void* d_ws, size_t ws_size,
                              hipStream_t stream) {
  const float* features = (const float*)d_in[0];
  const float* W1 = (const float*)d_in[1];
  const float* b1 = (const float*)d_in[2];
  const float* W2 = (const float*)d_in[3];
  const float* b2 = (const float*)d_in[4];
  const float* Wg = (const float*)d_in[5];
  const float* bg = (const float*)d_in[6];
  float* out = (float*)d_out;

  char* ws = (char*)d_ws;
  ushort_t* featbf = (ushort_t*)ws;                  // 16 MB   [F][B][D]
  ushort_t* w1t    = (ushort_t*)(ws + 16777216);     // 32 MB   [F][E][H][D]
  ushort_t* w2t    = (ushort_t*)(ws + 50331648);     // 32 MB   [F][E][O][H]
  float*    g2     = (float*)(ws + 83886080);        // 0.5 MB  [F][B][E]
  ushort_t* Hf     = (ushort_t*)(ws + 84410368);     // 256 MB merged / 64 MB per-f
  const bool big = ws_size >= (size_t)386400256;
  ushort_t* part   = big ? (ushort_t*)(ws + 352845824)   // 32 MB [F*2][B][O] bf16
                         : (ushort_t*)(ws + 151519232);

  prep_kernel<<<F_ * B_, 64, 0, stream>>>(features, Wg, bg, g2, featbf);
  transpose_cast_kernel<<<dim3(H_ / 64, D_ / 64, F_ * E_), 256, 0, stream>>>(W1, w1t, D_, H_);
  transpose_cast_kernel<<<dim3(O_ / 64, H_ / 64, F_ * E_), 256, 0, stream>>>(W2, w2t, H_, O_);

  if (big) {
    gemm1_kernel<<<2048, 256, 0, stream>>>(featbf, w1t, b1, g2, Hf, 0, (size_t)E_ * B_ * H_);
    gemm2_kernel<<<1024, 256, 0, stream>>>(Hf, w2t, b2, g2, part, 0, (size_t)E_ * B_ * H_);
  } else {
    for (int f = 0; f < F_; ++f) {
      gemm1_kernel<<<512, 256, 0, stream>>>(featbf, w1t, b1, g2, Hf, f, 0);
      gemm2_kernel<<<256, 256, 0, stream>>>(Hf, w2t, b2, g2, part, f, 0);
    }
  }
  reduce_kernel<<<B_ * O_ / 8 / 256, 256, 0, stream>>>(part, out);
}

// Round 6
// 655.910 us; speedup vs baseline: 1.3455x; 1.3455x over previous
//
#include <hip/hip_runtime.h>

// MultiFeatureMOE: F=4, E=8, B=4096, D=512, H=1024, O=512.
// Round 13: 256-wide 2-phase k-half-progressive engine (m201-style T2+T3+T4+T5
// adapted to short K). Key idea vs rounds 8-12: intensity 128 FLOP/B (256-wide
// tiles) to beat the per-CU L2-feed wall, with counted vmcnt that NEVER drains:
// K-tile (BK=64) split into two 32-k subtiles stored separately (64B rows);
// phase kh consumes only subtiles staged 2 phases earlier -> steady vmcnt(4)
// (gemm1) / vmcnt(3) (gemm2) with only 2 LDS buffers.
//  - gemm1: 256x256, 8 K-tiles (D=512), grid 512/f, 512 thr (8 waves 4Mx2N,
//    wave 64x256-> acc[4][8]); LDS 128KB; per phase: 12 asm ds_read_b128,
//    4 global_load_lds, 32 MFMA.
//  - gemm2: 256x128, K chained over 2 experts = 32 K-tiles, grid 256/f (full
//    chip), acc[4][4]; LDS 96KB; per phase: 8 reads, 3 loads, 16 MFMA.
//  - 64B-row swizzle g(r)=(r>>1)&3: store chunk (t&3)^((t>>3)&3), read chunk
//    q^((lr>>1)&3) -> 2 lanes/bank-group (free).

#define F_ 4
#define E_ 8
#define B_ 4096
#define D_ 512
#define H_ 1024
#define O_ 512

typedef unsigned short ushort_t;
typedef __bf16 bf16x8 __attribute__((ext_vector_type(8)));
typedef float f32x4 __attribute__((ext_vector_type(4)));
typedef unsigned short ushort8_t __attribute__((ext_vector_type(8)));

__device__ inline ushort_t f2bf(float f) {
  union { float f; unsigned u; } v; v.f = f;
  unsigned r = v.u + 0x7FFFu + ((v.u >> 16) & 1u);  // RNE
  return (ushort_t)(r >> 16);
}
__device__ inline float bf2f(ushort_t u) {
  union { unsigned u; float f; } v; v.u = ((unsigned)u) << 16;
  return v.f;
}

__device__ inline void async16(const void* g, void* l) {
  __builtin_amdgcn_global_load_lds(
      (const __attribute__((address_space(1))) unsigned int*)g,
      (__attribute__((address_space(3))) unsigned int*)l, 16, 0, 0);
}

__device__ inline unsigned ldsOff(const void* p) {
  return (unsigned)(unsigned long long)(const __attribute__((address_space(3))) char*)p;
}
// raw ds_read_b128 — invisible to SIInsertWaitcnts' LDS-DMA alias tracking
__device__ inline bf16x8 dsr128(unsigned byteOff) {
  bf16x8 r;
  asm volatile("ds_read_b128 %0, %1" : "=v"(r) : "v"(byteOff));
  return r;
}

#define LGKM0 asm volatile("s_waitcnt lgkmcnt(0)" ::: "memory")
#define VM4 asm volatile("s_waitcnt vmcnt(4)" ::: "memory")
#define VM3 asm volatile("s_waitcnt vmcnt(3)" ::: "memory")
#define VM0 asm volatile("s_waitcnt vmcnt(0)" ::: "memory")
#define SCB __builtin_amdgcn_sched_barrier(0)
#define SBAR __builtin_amdgcn_s_barrier()

// ---------------- prep: gate softmax (fp32) + feature bf16 cast, fused ----------------
__global__ void prep_kernel(const float* __restrict__ features, const float* __restrict__ Wg,
                            const float* __restrict__ bg, float* __restrict__ g2,
                            ushort_t* __restrict__ featbf) {
  const int fb = blockIdx.x;
  const int f = fb >> 12, b = fb & (B_ - 1);
  const int lane = threadIdx.x;
  const float* feat = features + ((size_t)f * B_ + b) * D_;
  const float* wg = Wg + (size_t)f * D_ * E_;
  const int d0 = lane * 8;
  float ff[8];
  *(float4*)&ff[0] = *(const float4*)&feat[d0];
  *(float4*)&ff[4] = *(const float4*)&feat[d0 + 4];
  ushort8_t u;
#pragma unroll
  for (int k = 0; k < 8; ++k) u[k] = f2bf(ff[k]);
  *(ushort8_t*)&featbf[((size_t)f * B_ + b) * D_ + d0] = u;

  float acc[E_] = {0.f, 0.f, 0.f, 0.f, 0.f, 0.f, 0.f, 0.f};
#pragma unroll
  for (int k = 0; k < 8; ++k) {
    const float fv = ff[k];
    const float4 w0 = ((const float4*)(wg + (size_t)(d0 + k) * E_))[0];
    const float4 w1 = ((const float4*)(wg + (size_t)(d0 + k) * E_))[1];
    acc[0] += fv * w0.x; acc[1] += fv * w0.y; acc[2] += fv * w0.z; acc[3] += fv * w0.w;
    acc[4] += fv * w1.x; acc[5] += fv * w1.y; acc[6] += fv * w1.z; acc[7] += fv * w1.w;
  }
#pragma unroll
  for (int off = 32; off >= 1; off >>= 1)
#pragma unroll
    for (int e = 0; e < E_; ++e) acc[e] += __shfl_xor(acc[e], off, 64);
  float lg[E_], mx = -1e30f;
#pragma unroll
  for (int e = 0; e < E_; ++e) { lg[e] = acc[e] + bg[f * E_ + e]; mx = fmaxf(mx, lg[e]); }
  float s = 0.f;
#pragma unroll
  for (int e = 0; e < E_; ++e) { lg[e] = __expf(lg[e] - mx); s += lg[e]; }
  const float inv = 1.f / (s * (float)F_);
  if (lane < E_) g2[((size_t)f * B_ + b) * E_ + lane] = lg[lane] * inv;
}

// ------------- batched transpose+cast: [R][C] fp32 -> [C][R] bf16 -------------
__global__ void transpose_cast_kernel(const float* __restrict__ in, ushort_t* __restrict__ out,
                                      int R, int C) {
  __shared__ float tile[64][65];
  const size_t zoff = (size_t)blockIdx.z * R * C;
  in += zoff; out += zoff;
  const int tx = threadIdx.x & 63, ty = threadIdx.x >> 6;
  const int r0 = blockIdx.y * 64, c0 = blockIdx.x * 64;
#pragma unroll
  for (int i = 0; i < 16; ++i) {
    const int r = ty + i * 4;
    tile[r][tx] = in[(size_t)(r0 + r) * C + c0 + tx];
  }
  __syncthreads();
#pragma unroll
  for (int i = 0; i < 16; ++i) {
    const int c = ty + i * 4;
    out[(size_t)(c0 + c) * R + r0 + tx] = f2bf(tile[tx][c]);
  }
}

// =============== GEMM1: 256x256, BK=64 as 2x32-k subtiles, 2 buffers ===============
// Buffer (64KB): Akh0[256r x 64B]@0, Akh1@16384, Bkh0@32768, Bkh1@49152.
// Stage (per tile,kh): 4 async16/thread. Phase (kt,kh): vmcnt(4); barrier;
// 12 ds_read_b128; stage (kt+1,kh); lgkm0; 32 MFMA.
// Waves 4Mx2N: wave-tile 64m x 256n. acc[i][j]: m=wm*64+i*16+lr,
// n = wn*128 + j*16 + q*4 + {0..3}.

#define STG1(ktn, kh) { \
    char* d_ = (char*)lds + (((ktn) & 1) << 16) + (kh) * 16384 + t * 16; \
    const int ko_ = (ktn) * 64 + (kh) * 32; \
    async16(aT + ko_, d_); \
    async16(aT + 128 * D_ + ko_, d_ + 8192); \
    async16(bT + ko_, d_ + 32768); \
    async16(bT + 128 * D_ + ko_, d_ + 40960); }

#define PH1(kt, kh, DOSTG, VMS) { \
    VMS; \
    asm volatile("" ::: "memory"); SBAR; SCB; \
    const unsigned sb_ = ldsB + (unsigned)(((kt) & 1) << 16) + (kh) * 16384u; \
    bf16x8 af[4], bfr[8]; \
    _Pragma("unroll") for (int i_ = 0; i_ < 4; ++i_) af[i_] = dsr128(sb_ + aRd + i_ * 1024u); \
    _Pragma("unroll") for (int j_ = 0; j_ < 8; ++j_) bfr[j_] = dsr128(sb_ + 32768u + bRd + j_ * 1024u); \
    if (DOSTG) { STG1((kt) + 1, kh); } \
    LGKM0; SCB; \
    __builtin_amdgcn_s_setprio(1); \
    _Pragma("unroll") for (int i_ = 0; i_ < 4; ++i_) \
      _Pragma("unroll") for (int j_ = 0; j_ < 8; ++j_) \
        acc[i_][j_] = __builtin_amdgcn_mfma_f32_16x16x32_bf16(bfr[j_], af[i_], acc[i_][j_], 0, 0, 0); \
    __builtin_amdgcn_s_setprio(0); SCB; }

__global__ __launch_bounds__(512, 2) void gemm1_kernel(
    const ushort_t* __restrict__ featbf, const ushort_t* __restrict__ w1t,
    const float* __restrict__ b1, const float* __restrict__ g2,
    ushort_t* __restrict__ Hf, int f) {
  __shared__ __align__(16) ushort_t lds[65536];  // 128 KB
  const int id = blockIdx.x;
  const int e = id & 7;
  const int s = id >> 3;          // 0..63
  const int n0 = (s & 3) * 256;   // h
  const int m0 = (s >> 2) * 256;  // b
  const float* b1e = b1 + ((size_t)f * E_ + e) * H_;
  const float* g2f = g2 + (size_t)f * B_ * E_;
  ushort_t* HfE = Hf + (size_t)e * B_ * H_;

  const int t = threadIdx.x, lane = t & 63, w = t >> 6;
  const int wm = w >> 1, wn = w & 1;        // wm 0..3, wn 0..1
  const int lr = lane & 15, q = lane >> 4;  // q 0..3
  const unsigned ldsB = ldsOff(lds);
  const unsigned csw = (unsigned)((q ^ ((lr >> 1) & 3)) << 4);
  const unsigned aRd = (unsigned)((wm * 64 + lr) * 64) + csw;
  const unsigned bRd = (unsigned)((wn * 128 + lr) * 64) + csw;

  const int cc = (t & 3) ^ ((t >> 3) & 3);  // staging source chunk (lane-pure)
  const ushort_t* aT = featbf + (size_t)f * B_ * D_ + (size_t)(m0 + (t >> 2)) * D_ + cc * 8;
  const ushort_t* bT = w1t + ((size_t)f * E_ + e) * ((size_t)H_ * D_) +
                       (size_t)(n0 + (t >> 2)) * D_ + cc * 8;

  f32x4 acc[4][8];
#pragma unroll
  for (int i = 0; i < 4; ++i)
#pragma unroll
    for (int j = 0; j < 8; ++j) acc[i][j] = (f32x4){0.f, 0.f, 0.f, 0.f};

  // prologue: stage tile 0 (both k-halves)
  STG1(0, 0); STG1(0, 1);

  // 8 K-tiles (D=512/64): steady vmcnt(4); final phase vmcnt(0).
  for (int kt = 0; kt < 7; ++kt) {
    PH1(kt, 0, true, VM4);
    PH1(kt, 1, true, VM4);
  }
  PH1(7, 0, false, VM4);
  PH1(7, 1, false, VM0);

  // epilogue: bias+relu+gate -> cb [128][264] per M-half -> coalesced stores
  asm volatile("" ::: "memory"); SBAR; SCB;
  ushort_t* cb = lds;
#pragma unroll
  for (int mh = 0; mh < 2; ++mh) {
    if ((wm >> 1) == mh) {
#pragma unroll
      for (int i = 0; i < 4; ++i) {
        const int rl = (wm & 1) * 64 + i * 16 + lr;  // 0..127
        const float gv = g2f[(size_t)(m0 + mh * 128 + rl) * E_ + e];
#pragma unroll
        for (int j = 0; j < 8; ++j) {
          const int nl = wn * 128 + j * 16 + q * 4;  // 0..255
          const float4 bb = *(const float4*)&b1e[n0 + nl];
          ushort4 o;
          o.x = f2bf(fmaxf(acc[i][j][0] + bb.x, 0.f) * gv);
          o.y = f2bf(fmaxf(acc[i][j][1] + bb.y, 0.f) * gv);
          o.z = f2bf(fmaxf(acc[i][j][2] + bb.z, 0.f) * gv);
          o.w = f2bf(fmaxf(acc[i][j][3] + bb.w, 0.f) * gv);
          *(ushort4*)&cb[rl * 264 + nl] = o;
        }
      }
    }
    __syncthreads();
    {
      const int row = t >> 2, seg = t & 3;  // 128 rows x 4 segs of 64 ushorts
      const ushort_t* src = &cb[row * 264 + seg * 64];
      ushort_t* dst = HfE + (size_t)(m0 + mh * 128 + row) * H_ + n0 + seg * 64;
#pragma unroll
      for (int c2 = 0; c2 < 8; ++c2)
        *(ushort8_t*)(dst + c2 * 8) = *(const ushort8_t*)(src + c2 * 8);
    }
    __syncthreads();
  }
}

// =============== GEMM2: 256x128, K = 2 experts x 1024 = 32 K-tiles ===============
// Buffer (48KB): Akh0@0, Akh1@16384, Bkh0@32768, Bkh1@40960. 2 buffers = 96KB.
// Stage per (tile,kh): 3 async16/thread -> steady vmcnt(3).
// Waves 4Mx2N: wave-tile 64m x 128n. acc[4][4].

#define STG2(ktn, kh) { \
    const size_t eo_ = (size_t)((ktn) >> 4); \
    const int ko_ = ((ktn) & 15) * 64 + (kh) * 32; \
    const ushort_t* a_ = aT + eo_ * ((size_t)B_ * H_) + ko_; \
    const ushort_t* b_ = bT + eo_ * ((size_t)O_ * H_) + ko_; \
    char* dA_ = (char*)lds + (((ktn) & 1) ? 49152 : 0) + (kh) * 16384 + t * 16; \
    char* dB_ = (char*)lds + (((ktn) & 1) ? 49152 : 0) + 32768 + (kh) * 8192 + t * 16; \
    async16(a_, dA_); \
    async16(a_ + 128 * H_, dA_ + 8192); \
    async16(b_, dB_); }

#define PH2(kt, kh, DOSTG, VMS) { \
    VMS; \
    asm volatile("" ::: "memory"); SBAR; SCB; \
    const unsigned sb_ = ldsB + (unsigned)(((kt) & 1) ? 49152 : 0); \
    bf16x8 af[4], bfr[4]; \
    _Pragma("unroll") for (int i_ = 0; i_ < 4; ++i_) \
      af[i_] = dsr128(sb_ + (kh) * 16384u + aRd + i_ * 1024u); \
    _Pragma("unroll") for (int j_ = 0; j_ < 4; ++j_) \
      bfr[j_] = dsr128(sb_ + 32768u + (kh) * 8192u + bRd + j_ * 1024u); \
    if (DOSTG) { STG2((kt) + 1, kh); } \
    LGKM0; SCB; \
    __builtin_amdgcn_s_setprio(1); \
    _Pragma("unroll") for (int i_ = 0; i_ < 4; ++i_) \
      _Pragma("unroll") for (int j_ = 0; j_ < 4; ++j_) \
        acc[i_][j_] = __builtin_amdgcn_mfma_f32_16x16x32_bf16(bfr[j_], af[i_], acc[i_][j_], 0, 0, 0); \
    __builtin_amdgcn_s_setprio(0); SCB; }

__global__ __launch_bounds__(512, 2) void gemm2_kernel(
    const ushort_t* __restrict__ Hf, const ushort_t* __restrict__ w2t,
    const float* __restrict__ b2, const float* __restrict__ g2,
    ushort_t* __restrict__ part, int f) {
  __shared__ __align__(16) ushort_t lds[49152];  // 96 KB
  const int id = blockIdx.x;      // 0..255
  const int grp = id & 3;
  const int s = id >> 2;          // 0..63
  const int n0 = (s & 3) * 128;   // o
  const int m0 = (s >> 2) * 256;  // b
  const int e0 = grp * 2;
  const float* g2f = g2 + (size_t)f * B_ * E_;

  const int t = threadIdx.x, lane = t & 63, w = t >> 6;
  const int wm = w >> 1, wn = w & 1;        // wm 0..3, wn 0..1
  const int lr = lane & 15, q = lane >> 4;
  const unsigned ldsB = ldsOff(lds);
  const unsigned csw = (unsigned)((q ^ ((lr >> 1) & 3)) << 4);
  const unsigned aRd = (unsigned)((wm * 64 + lr) * 64) + csw;
  const unsigned bRd = (unsigned)((wn * 64 + lr) * 64) + csw;

  const int cc = (t & 3) ^ ((t >> 3) & 3);
  const ushort_t* aT = Hf + (size_t)e0 * B_ * H_ + (size_t)(m0 + (t >> 2)) * H_ + cc * 8;
  const ushort_t* bT = w2t + ((size_t)f * E_ + e0) * ((size_t)O_ * H_) +
                       (size_t)(n0 + (t >> 2)) * H_ + cc * 8;

  f32x4 acc[4][4];
#pragma unroll
  for (int i = 0; i < 4; ++i)
#pragma unroll
    for (int j = 0; j < 4; ++j) acc[i][j] = (f32x4){0.f, 0.f, 0.f, 0.f};

  STG2(0, 0); STG2(0, 1);

  // 32 K-tiles (2 experts x H/64): steady vmcnt(3); final phase vmcnt(0).
  for (int kt = 0; kt < 31; ++kt) {
    PH2(kt, 0, true, VM3);
    PH2(kt, 1, true, VM3);
  }
  PH2(31, 0, false, VM3);
  PH2(31, 1, false, VM0);

  // epilogue: acc + g0*b2e0 + g1*b2e1 -> cb [128][136] per M-half -> stores
  asm volatile("" ::: "memory"); SBAR; SCB;
  ushort_t* cb = lds;
  const float* b2e0 = b2 + ((size_t)f * E_ + e0) * O_;
  const float* b2e1 = b2e0 + O_;
  ushort_t* dstP = part + (size_t)(f * 4 + grp) * ((size_t)B_ * O_);
#pragma unroll
  for (int mh = 0; mh < 2; ++mh) {
    if ((wm >> 1) == mh) {
#pragma unroll
      for (int i = 0; i < 4; ++i) {
        const int rl = (wm & 1) * 64 + i * 16 + lr;  // 0..127
        const size_t gr = (size_t)(m0 + mh * 128 + rl) * E_ + e0;
        const float gv0 = g2f[gr], gv1 = g2f[gr + 1];
#pragma unroll
        for (int j = 0; j < 4; ++j) {
          const int nl = wn * 64 + j * 16 + q * 4;  // 0..127
          const int n = n0 + nl;
          const float4 c0 = *(const float4*)&b2e0[n];
          const float4 c1 = *(const float4*)&b2e1[n];
          ushort4 o;
          o.x = f2bf(acc[i][j][0] + gv0 * c0.x + gv1 * c1.x);
          o.y = f2bf(acc[i][j][1] + gv0 * c0.y + gv1 * c1.y);
          o.z = f2bf(acc[i][j][2] + gv0 * c0.z + gv1 * c1.z);
          o.w = f2bf(acc[i][j][3] + gv0 * c0.w + gv1 * c1.w);
          *(ushort4*)&cb[rl * 136 + nl] = o;
        }
      }
    }
    __syncthreads();
    {
      const int row = t >> 2, seg = t & 3;  // 128 rows x 4 segs of 32 ushorts
      const ushort_t* src = &cb[row * 136 + seg * 32];
      ushort_t* dst = dstP + (size_t)(m0 + mh * 128 + row) * O_ + n0 + seg * 32;
#pragma unroll
      for (int c2 = 0; c2 < 4; ++c2)
        *(ushort8_t*)(dst + c2 * 8) = *(const ushort8_t*)(src + c2 * 8);
    }
    __syncthreads();
  }
}

// ---------------- final reduce: out = sum over 16 bf16 slabs ----------------
__global__ void reduce_kernel(const ushort_t* __restrict__ part, float* __restrict__ out) {
  const size_t p = ((size_t)blockIdx.x * 256 + threadIdx.x) * 8;
  float s[8] = {0.f, 0.f, 0.f, 0.f, 0.f, 0.f, 0.f, 0.f};
#pragma unroll
  for (int k = 0; k < F_ * 4; ++k) {
    const ushort8_t u = *(const ushort8_t*)&part[(size_t)k * (B_ * O_) + p];
#pragma unroll
    for (int j = 0; j < 8; ++j) s[j] += bf2f(u[j]);
  }
  float4 o0 = {s[0], s[1], s[2], s[3]}, o1 = {s[4], s[5], s[6], s[7]};
  *(float4*)&out[p] = o0;
  *(float4*)&out[p + 4] = o1;
}

extern "C" void kernel_launch(void* const* d_in, const int* in_sizes, int n_in,
                              void* d_out, int out_size, void* d_ws, size_t ws_size,
                              hipStream_t stream) {
  const float* features = (const float*)d_in[0];
  const float* W1 = (const float*)d_in[1];
  const float* b1 = (const float*)d_in[2];
  const float* W2 = (const float*)d_in[3];
  const float* b2 = (const float*)d_in[4];
  const float* Wg = (const float*)d_in[5];
  const float* bg = (const float*)d_in[6];
  float* out = (float*)d_out;

  char* ws = (char*)d_ws;
  ushort_t* featbf = (ushort_t*)ws;                  // 16 MB   [F][B][D]
  ushort_t* w1t    = (ushort_t*)(ws + 16777216);     // 32 MB   [F][E][H][D]
  ushort_t* w2t    = (ushort_t*)(ws + 50331648);     // 32 MB   [F][E][O][H]
  float*    g2     = (float*)(ws + 83886080);        // 0.5 MB  [F][B][E]
  ushort_t* Hf     = (ushort_t*)(ws + 84410368);     // 64 MB   [E][B][H] (per-f)
  ushort_t* part   = (ushort_t*)(ws + 151519232);    // 64 MB   [F*4][B][O] bf16

  prep_kernel<<<F_ * B_, 64, 0, stream>>>(features, Wg, bg, g2, featbf);
  transpose_cast_kernel<<<dim3(H_ / 64, D_ / 64, F_ * E_), 256, 0, stream>>>(W1, w1t, D_, H_);
  transpose_cast_kernel<<<dim3(O_ / 64, H_ / 64, F_ * E_), 256, 0, stream>>>(W2, w2t, H_, O_);

  for (int f = 0; f < F_; ++f) {
    gemm1_kernel<<<512, 512, 0, stream>>>(featbf, w1t, b1, g2, Hf, f);
    gemm2_kernel<<<256, 512, 0, stream>>>(Hf, w2t, b2, g2, part, f);
  }
  reduce_kernel<<<B_ * O_ / 8 / 256, 256, 0, stream>>>(part, out);
}